// Round 1
// baseline (825.291 us; speedup 1.0000x reference)
//
#include <hip/hip_runtime.h>
#include <hip/hip_bf16.h>
#include <cstdint>
#include <cstddef>

using bf16 = __hip_bfloat16;
typedef __bf16 bf16x8 __attribute__((ext_vector_type(8)));
typedef float f32x4 __attribute__((ext_vector_type(4)));

// ---- constants for this problem ----
#define BB 16
#define TT 1024
#define DD 1024
#define EE 64
#define MREAL 16368   // (TT-1)*BB
#define MPAD  16384
#define NCHUNK 16
#define CHUNK 64

__device__ __forceinline__ void gload_lds16(const void* g, void* l) {
  __builtin_amdgcn_global_load_lds((const __attribute__((address_space(1))) void*)g,
                                   (__attribute__((address_space(3))) void*)l,
                                   16, 0, 0);
}

__device__ __forceinline__ float sigmoidf_(float x) {
  return 1.0f / (1.0f + __expf(-x));
}

// ---------------- fp32 -> bf16 weight conversion ----------------
__global__ void f2b(const float* __restrict__ src, bf16* __restrict__ dst, int n) {
  int i = (blockIdx.x * blockDim.x + threadIdx.x) * 4;
  if (i < n) {
    float4 v = *reinterpret_cast<const float4*>(src + i);
    dst[i + 0] = __float2bfloat16(v.x);
    dst[i + 1] = __float2bfloat16(v.y);
    dst[i + 2] = __float2bfloat16(v.z);
    dst[i + 3] = __float2bfloat16(v.w);
  }
}

// ---------------- EMA pass 1: chunk-local endpoints ----------------
// tid = c*16384 + b*1024 + d ; 262144 threads
__global__ void ema_ends(const float* __restrict__ seq, const float* __restrict__ beta_raw,
                         float* __restrict__ ends) {
  int tid = blockIdx.x * blockDim.x + threadIdx.x;
  int d = tid & (DD - 1);
  int b = (tid >> 10) & (BB - 1);
  int c = tid >> 14;
  float beta = sigmoidf_(beta_raw[d]);
  int t0 = c * CHUNK;
  int len = min(CHUNK, (TT - 1) - t0);
  const float* p = seq + (size_t)b * TT * DD + (size_t)t0 * DD + d;
  float h = 0.0f;
#pragma unroll 8
  for (int j = 0; j < len; ++j) h = fmaf(beta, h, p[(size_t)j * DD]);
  ends[tid] = h;
}

// ---------------- EMA pass 2: carry combine (per chain) ----------------
// tid = b*1024 + d ; 16384 threads
__global__ void ema_carry(const float* __restrict__ ends, const float* __restrict__ beta_raw,
                          float* __restrict__ carry) {
  int tid = blockIdx.x * blockDim.x + threadIdx.x;
  int d = tid & (DD - 1);
  float beta = sigmoidf_(beta_raw[d]);
  // beta^64 via 6 squarings
  float bl = beta;
  bl *= bl; bl *= bl; bl *= bl; bl *= bl; bl *= bl; bl *= bl;
  float run = 0.0f;
#pragma unroll
  for (int c = 0; c < NCHUNK; ++c) {
    carry[c * (BB * DD) + tid] = run;
    run = ends[c * (BB * DD) + tid] + bl * run;
  }
}

// ---------------- EMA pass 3: recompute + write A = [x | h] in bf16 ----------------
__global__ void ema_write(const float* __restrict__ seq, const float* __restrict__ beta_raw,
                          const float* __restrict__ carry, bf16* __restrict__ A) {
  int tid = blockIdx.x * blockDim.x + threadIdx.x;
  int d = tid & (DD - 1);
  int b = (tid >> 10) & (BB - 1);
  int c = tid >> 14;
  float beta = sigmoidf_(beta_raw[d]);
  int t0 = c * CHUNK;
  int len = min(CHUNK, (TT - 1) - t0);
  const float* p = seq + (size_t)b * TT * DD + (size_t)t0 * DD + d;
  float h = carry[tid];
#pragma unroll 4
  for (int j = 0; j < len; ++j) {
    float x = p[(size_t)j * DD];
    h = fmaf(beta, h, x);
    size_t m = (size_t)(t0 + j) * BB + b;
    A[m * (2 * DD) + d]      = __float2bfloat16(x);
    A[m * (2 * DD) + DD + d] = __float2bfloat16(h);
  }
}

// ---------------- main GEMM: C = act(A @ B^T + bias) ----------------
// A: (MPAD, K) bf16 row-major. B: (N, K) bf16 row-major (i.e. B^T layout).
// 128x128 tile, BK=32, 256 threads = 4 waves in 2x2, 4x4 16x16x32 MFMA per wave.
template <bool RELU, bool DUAL_OUT>
__global__ __launch_bounds__(256)
void gemm_bt(const bf16* __restrict__ A, const bf16* __restrict__ B,
             const float* __restrict__ bias, bf16* __restrict__ outb,
             float* __restrict__ outf, int N, int K) {
  __shared__ alignas(16) bf16 As[128 * 32];
  __shared__ alignas(16) bf16 Bs[128 * 32];
  const int tid  = threadIdx.x;
  const int wave = tid >> 6;
  const int lane = tid & 63;
  const int bm = blockIdx.x * 128;
  const int bn = blockIdx.y * 128;

  // staging: each wave fills 2 KiB of each tile; lane -> base + lane*16 contiguous
  const int srow = wave * 32 + (lane >> 2);
  const int scol = (lane & 3) * 8;
  const bf16* gA0 = A + (size_t)(bm + srow) * K + scol;
  const bf16* gA1 = gA0 + (size_t)16 * K;
  const bf16* gB0 = B + (size_t)(bn + srow) * K + scol;
  const bf16* gB1 = gB0 + (size_t)16 * K;
  bf16* lA0 = &As[srow * 32 + scol];
  bf16* lA1 = lA0 + 16 * 32;
  bf16* lB0 = &Bs[srow * 32 + scol];
  bf16* lB1 = lB0 + 16 * 32;

  const int wm = (wave >> 1) * 64;
  const int wn = (wave & 1) * 64;
  const int lr = lane & 15;
  const int quad = lane >> 4;

  f32x4 acc[4][4] = {};

  for (int k0 = 0; k0 < K; k0 += 32) {
    __syncthreads();
    gload_lds16(gA0 + k0, lA0);
    gload_lds16(gA1 + k0, lA1);
    gload_lds16(gB0 + k0, lB0);
    gload_lds16(gB1 + k0, lB1);
    __syncthreads();
    bf16x8 af[4], bf_[4];
#pragma unroll
    for (int i = 0; i < 4; ++i)
      af[i] = *reinterpret_cast<const bf16x8*>(&As[(wm + i * 16 + lr) * 32 + quad * 8]);
#pragma unroll
    for (int j = 0; j < 4; ++j)
      bf_[j] = *reinterpret_cast<const bf16x8*>(&Bs[(wn + j * 16 + lr) * 32 + quad * 8]);
#pragma unroll
    for (int i = 0; i < 4; ++i)
#pragma unroll
      for (int j = 0; j < 4; ++j)
        acc[i][j] = __builtin_amdgcn_mfma_f32_16x16x32_bf16(af[i], bf_[j], acc[i][j], 0, 0, 0);
  }

#pragma unroll
  for (int i = 0; i < 4; ++i) {
#pragma unroll
    for (int j = 0; j < 4; ++j) {
      const int n = bn + wn + j * 16 + lr;
      const float bv = bias[n];
#pragma unroll
      for (int r = 0; r < 4; ++r) {
        const int m = bm + wm + i * 16 + quad * 4 + r;
        float v = acc[i][j][r] + bv;
        if (RELU) v = fmaxf(v, 0.0f);
        outb[(size_t)m * N + n] = __float2bfloat16(v);
        if (DUAL_OUT) {
          if (m < MREAL) outf[(size_t)m * N + n] = v;
        }
      }
    }
  }
}

// ---------------- router GEMM: logits = (Xhat @ Ww^T + Wb) * pi ----------------
// A: (MPAD, 1024) bf16, B: (64, 1024) bf16. 64x64 tile, 256 threads.
__global__ __launch_bounds__(256)
void gemm_router(const bf16* __restrict__ A, const bf16* __restrict__ B,
                 const float* __restrict__ Wb, const float* __restrict__ pi,
                 float* __restrict__ out) {
  const int K = DD;
  __shared__ alignas(16) bf16 As[64 * 32];
  __shared__ alignas(16) bf16 Bs[64 * 32];
  const int tid  = threadIdx.x;
  const int wave = tid >> 6;
  const int lane = tid & 63;
  const int bm = blockIdx.x * 64;
  const int srow = wave * 16 + (lane >> 2);
  const int scol = (lane & 3) * 8;
  const bf16* gA = A + (size_t)(bm + srow) * K + scol;
  const bf16* gB = B + (size_t)srow * K + scol;
  bf16* lA = &As[srow * 32 + scol];
  bf16* lB = &Bs[srow * 32 + scol];
  const int lr = lane & 15;
  const int quad = lane >> 4;
  f32x4 acc[4] = {};
  for (int k0 = 0; k0 < K; k0 += 32) {
    __syncthreads();
    gload_lds16(gA + k0, lA);
    gload_lds16(gB + k0, lB);
    __syncthreads();
    bf16x8 af = *reinterpret_cast<const bf16x8*>(&As[(wave * 16 + lr) * 32 + quad * 8]);
#pragma unroll
    for (int j = 0; j < 4; ++j) {
      bf16x8 bf_ = *reinterpret_cast<const bf16x8*>(&Bs[(j * 16 + lr) * 32 + quad * 8]);
      acc[j] = __builtin_amdgcn_mfma_f32_16x16x32_bf16(af, bf_, acc[j], 0, 0, 0);
    }
  }
#pragma unroll
  for (int j = 0; j < 4; ++j) {
    const int e = j * 16 + lr;
    const float wb = Wb[e], pv = pi[e];
#pragma unroll
    for (int r = 0; r < 4; ++r) {
      const int m = bm + wave * 16 + quad * 4 + r;
      if (m < MREAL) out[(size_t)m * EE + e] = (acc[j][r] + wb) * pv;
    }
  }
}

extern "C" void kernel_launch(void* const* d_in, const int* in_sizes, int n_in,
                              void* d_out, int out_size, void* d_ws, size_t ws_size,
                              hipStream_t stream) {
  const float* seq      = (const float*)d_in[0];
  const float* pi       = (const float*)d_in[1];
  const float* beta_raw = (const float*)d_in[2];
  const float* p1_w     = (const float*)d_in[3];
  const float* p1_b     = (const float*)d_in[4];
  const float* p2_w     = (const float*)d_in[5];
  const float* p2_b     = (const float*)d_in[6];
  const float* W_w      = (const float*)d_in[7];
  const float* W_b      = (const float*)d_in[8];

  // workspace layout (bytes); Xhat_bf16 aliases A (A dead after GEMM1)
  constexpr size_t A_off    = 0;
  constexpr size_t A_sz     = (size_t)MPAD * 2 * DD * sizeof(bf16);   //  64 MiB
  constexpr size_t W1_off   = A_off + A_sz;
  constexpr size_t W1_sz    = (size_t)4 * DD * 2 * DD * sizeof(bf16); //  16 MiB
  constexpr size_t HID_off  = W1_off + W1_sz;
  constexpr size_t HID_sz   = (size_t)MPAD * 4 * DD * sizeof(bf16);   // 128 MiB
  constexpr size_t W2_off   = HID_off + HID_sz;
  constexpr size_t W2_sz    = (size_t)DD * 4 * DD * sizeof(bf16);     //   8 MiB
  constexpr size_t W3_off   = W2_off + W2_sz;
  constexpr size_t W3_sz    = (size_t)EE * DD * sizeof(bf16);
  constexpr size_t ENDS_off = W3_off + W3_sz;
  constexpr size_t ENDS_sz  = (size_t)NCHUNK * BB * DD * sizeof(float);
  constexpr size_t CARRY_off = ENDS_off + ENDS_sz;

  char* ws = (char*)d_ws;
  bf16*  Abuf = (bf16*)(ws + A_off);
  bf16*  W1   = (bf16*)(ws + W1_off);
  bf16*  HID  = (bf16*)(ws + HID_off);
  bf16*  W2   = (bf16*)(ws + W2_off);
  bf16*  W3   = (bf16*)(ws + W3_off);
  float* ENDS = (float*)(ws + ENDS_off);
  float* CARRY = (float*)(ws + CARRY_off);
  bf16*  XH   = (bf16*)(ws + A_off);  // alias of A

  float* out_logits = (float*)d_out;
  float* out_xhat   = out_logits + (size_t)MREAL * EE;

  // 1) weights -> bf16
  f2b<<<(4 * DD * 2 * DD / 4 + 255) / 256, 256, 0, stream>>>(p1_w, W1, 4 * DD * 2 * DD);
  f2b<<<(DD * 4 * DD / 4 + 255) / 256, 256, 0, stream>>>(p2_w, W2, DD * 4 * DD);
  f2b<<<(EE * DD / 4 + 255) / 256, 256, 0, stream>>>(W_w, W3, EE * DD);

  // 2) EMA scan (chunked 3-pass) -> A = [x | h] bf16
  ema_ends<<<NCHUNK * BB * DD / 256, 256, 0, stream>>>(seq, beta_raw, ENDS);
  ema_carry<<<BB * DD / 256, 256, 0, stream>>>(ENDS, beta_raw, CARRY);
  ema_write<<<NCHUNK * BB * DD / 256, 256, 0, stream>>>(seq, beta_raw, CARRY, Abuf);
  hipMemsetAsync(ws + A_off + (size_t)MREAL * 2 * DD * sizeof(bf16), 0,
                 (size_t)(MPAD - MREAL) * 2 * DD * sizeof(bf16), stream);

  // 3) GEMM1: hid = relu(A @ p1_w^T + b1)   (16384 x 4096, K=2048)
  gemm_bt<true, false><<<dim3(MPAD / 128, 4 * DD / 128), 256, 0, stream>>>(
      Abuf, W1, p1_b, HID, nullptr, 4 * DD, 2 * DD);

  // 4) GEMM2: x_hat = hid @ p2_w^T + b2     (16384 x 1024, K=4096) -> f32 out + bf16 ws
  gemm_bt<false, true><<<dim3(MPAD / 128, DD / 128), 256, 0, stream>>>(
      HID, W2, p2_b, XH, out_xhat, DD, 4 * DD);

  // 5) GEMM3: logits = (x_hat @ W_w^T + W_b) * pi   (16368 x 64, K=1024)
  gemm_router<<<MPAD / 64, 256, 0, stream>>>(XH, W3, W_b, pi, out_logits);
}

// Round 3
// 723.151 us; speedup vs baseline: 1.1412x; 1.1412x over previous
//
#include <hip/hip_runtime.h>
#include <hip/hip_bf16.h>
#include <cstdint>
#include <cstddef>

using bf16 = __hip_bfloat16;
typedef __bf16 bf16x8 __attribute__((ext_vector_type(8)));
typedef float f32x4 __attribute__((ext_vector_type(4)));
typedef float f32x16 __attribute__((ext_vector_type(16)));

// ---- constants for this problem ----
#define BB 16
#define TT 1024
#define DD 1024
#define EE 64
#define MREAL 16368   // (TT-1)*BB
#define MPAD  16384
#define NCHUNK 16
#define CHUNK 64

__device__ __forceinline__ void gload_lds16(const void* g, void* l) {
  __builtin_amdgcn_global_load_lds((const __attribute__((address_space(1))) void*)g,
                                   (__attribute__((address_space(3))) void*)l,
                                   16, 0, 0);
}

__device__ __forceinline__ float sigmoidf_(float x) {
  return 1.0f / (1.0f + __expf(-x));
}

// ---------------- fp32 -> bf16 weight conversion (8 elems/thread, 16B store) ----
__global__ void f2b(const float* __restrict__ src, bf16* __restrict__ dst, int n) {
  int i = (blockIdx.x * blockDim.x + threadIdx.x) * 8;
  if (i < n) {
    float4 v0 = *reinterpret_cast<const float4*>(src + i);
    float4 v1 = *reinterpret_cast<const float4*>(src + i + 4);
    alignas(16) bf16 tmp[8];
    tmp[0] = __float2bfloat16(v0.x); tmp[1] = __float2bfloat16(v0.y);
    tmp[2] = __float2bfloat16(v0.z); tmp[3] = __float2bfloat16(v0.w);
    tmp[4] = __float2bfloat16(v1.x); tmp[5] = __float2bfloat16(v1.y);
    tmp[6] = __float2bfloat16(v1.z); tmp[7] = __float2bfloat16(v1.w);
    *reinterpret_cast<float4*>(dst + i) = *reinterpret_cast<const float4*>(tmp);
  }
}

// ---------------- EMA pass 1: chunk-local endpoints ----------------
__global__ void ema_ends(const float* __restrict__ seq, const float* __restrict__ beta_raw,
                         float* __restrict__ ends) {
  int tid = blockIdx.x * blockDim.x + threadIdx.x;
  int d = tid & (DD - 1);
  int b = (tid >> 10) & (BB - 1);
  int c = tid >> 14;
  float beta = sigmoidf_(beta_raw[d]);
  int t0 = c * CHUNK;
  int len = min(CHUNK, (TT - 1) - t0);
  const float* p = seq + (size_t)b * TT * DD + (size_t)t0 * DD + d;
  float h = 0.0f;
#pragma unroll 8
  for (int j = 0; j < len; ++j) h = fmaf(beta, h, p[(size_t)j * DD]);
  ends[tid] = h;
}

// ---------------- EMA pass 2: carry combine (per chain) ----------------
__global__ void ema_carry(const float* __restrict__ ends, const float* __restrict__ beta_raw,
                          float* __restrict__ carry) {
  int tid = blockIdx.x * blockDim.x + threadIdx.x;
  int d = tid & (DD - 1);
  float beta = sigmoidf_(beta_raw[d]);
  float bl = beta;
  bl *= bl; bl *= bl; bl *= bl; bl *= bl; bl *= bl; bl *= bl;  // beta^64
  float run = 0.0f;
#pragma unroll
  for (int c = 0; c < NCHUNK; ++c) {
    carry[c * (BB * DD) + tid] = run;
    run = ends[c * (BB * DD) + tid] + bl * run;
  }
}

// ---------------- EMA pass 3: recompute + write A = [x | h] in bf16 ----------------
__global__ void ema_write(const float* __restrict__ seq, const float* __restrict__ beta_raw,
                          const float* __restrict__ carry, bf16* __restrict__ A) {
  int tid = blockIdx.x * blockDim.x + threadIdx.x;
  int d = tid & (DD - 1);
  int b = (tid >> 10) & (BB - 1);
  int c = tid >> 14;
  float beta = sigmoidf_(beta_raw[d]);
  int t0 = c * CHUNK;
  int len = min(CHUNK, (TT - 1) - t0);
  const float* p = seq + (size_t)b * TT * DD + (size_t)t0 * DD + d;
  float h = carry[tid];
#pragma unroll 4
  for (int j = 0; j < len; ++j) {
    float x = p[(size_t)j * DD];
    h = fmaf(beta, h, x);
    size_t m = (size_t)(t0 + j) * BB + b;
    A[m * (2 * DD) + d]      = __float2bfloat16(x);
    A[m * (2 * DD) + DD + d] = __float2bfloat16(h);
  }
}

// ---------------- main GEMM: C = act(A @ B^T + bias) ----------------
// A: (MPAD, K) bf16 row-major. B: (N, K) bf16 row-major.
// 128x128 tile, BK=64, 256 threads = 4 waves in 2x2, each wave 2x2 frags of
// 32x32x16 MFMA. LDS tiles 128x64 bf16 with XOR swizzle:
//   physical colgroup (16B units) = logical_cg ^ (row & 7), row stride 128B.
// grid.x = N/128 (fast, keeps weights L2-resident), grid.y = MPAD/128.
template <bool RELU, bool DUAL_OUT>
__global__ __launch_bounds__(256)
void gemm_bt(const bf16* __restrict__ A, const bf16* __restrict__ B,
             const float* __restrict__ bias, bf16* __restrict__ outb,
             float* __restrict__ outf, int N, int K) {
  __shared__ alignas(16) bf16 As[128 * 64];
  __shared__ alignas(16) bf16 Bs[128 * 64];
  const int tid  = threadIdx.x;
  const int wave = tid >> 6;
  const int lane = tid & 63;
  const int bm = blockIdx.y * 128;
  const int bn = blockIdx.x * 128;

  // --- staging: wave w fills rows [w*32, w*32+32) of each tile.
  // 4 instrs per tile, each covers 8 rows x 128B. lane l -> row +(l>>3),
  // physical cg = l&7, so source logical cg = (l&7) ^ (l>>3).
  const int srow8 = lane >> 3;                 // 0..7
  const int scg   = (lane & 7) ^ srow8;        // swizzled source colgroup
  const int strow = wave * 32 + srow8;         // row of instr t=0
  const bf16* gA = A + (size_t)(bm + strow) * K + scg * 8;
  const bf16* gB = B + (size_t)(bn + strow) * K + scg * 8;
  bf16* lA = &As[strow * 64 + (lane & 7) * 8];
  bf16* lB = &Bs[strow * 64 + (lane & 7) * 8];

  // --- fragment read addressing (32x32x16): m/n = lane&31, k = (lane>>5)*8+j
  const int lr   = lane & 31;
  const int half = lane >> 5;
  const int wm = (wave >> 1) * 64;
  const int wn = (wave & 1) * 64;
  const int aoff0 = (wm + lr) * 64;
  const int aoff1 = (wm + 32 + lr) * 64;
  const int boff0 = (wn + lr) * 64;
  const int boff1 = (wn + 32 + lr) * 64;
  int swz[4];
#pragma unroll
  for (int kk = 0; kk < 4; ++kk) swz[kk] = ((kk * 2 + half) ^ (lr & 7)) * 8;

  f32x16 acc00 = {}, acc01 = {}, acc10 = {}, acc11 = {};

  for (int k0 = 0; k0 < K; k0 += 64) {
    __syncthreads();
#pragma unroll
    for (int t = 0; t < 4; ++t) {
      gload_lds16(gA + (size_t)t * 8 * K + k0, lA + t * 8 * 64);
      gload_lds16(gB + (size_t)t * 8 * K + k0, lB + t * 8 * 64);
    }
    __syncthreads();
#pragma unroll
    for (int kk = 0; kk < 4; ++kk) {
      bf16x8 a0 = *reinterpret_cast<const bf16x8*>(&As[aoff0 + swz[kk]]);
      bf16x8 a1 = *reinterpret_cast<const bf16x8*>(&As[aoff1 + swz[kk]]);
      bf16x8 b0 = *reinterpret_cast<const bf16x8*>(&Bs[boff0 + swz[kk]]);
      bf16x8 b1 = *reinterpret_cast<const bf16x8*>(&Bs[boff1 + swz[kk]]);
      acc00 = __builtin_amdgcn_mfma_f32_32x32x16_bf16(a0, b0, acc00, 0, 0, 0);
      acc01 = __builtin_amdgcn_mfma_f32_32x32x16_bf16(a0, b1, acc01, 0, 0, 0);
      acc10 = __builtin_amdgcn_mfma_f32_32x32x16_bf16(a1, b0, acc10, 0, 0, 0);
      acc11 = __builtin_amdgcn_mfma_f32_32x32x16_bf16(a1, b1, acc11, 0, 0, 0);
    }
  }

  // epilogue: C/D layout col = lane&31, row = (r&3) + 8*(r>>2) + 4*half
  const f32x16* accs[4] = {&acc00, &acc01, &acc10, &acc11};
#pragma unroll
  for (int i = 0; i < 2; ++i) {
#pragma unroll
    for (int j = 0; j < 2; ++j) {
      const f32x16& a = *accs[i * 2 + j];
      const int n = bn + wn + j * 32 + lr;
      const float bv = bias[n];
#pragma unroll
      for (int r = 0; r < 16; ++r) {
        const int m = bm + wm + i * 32 + (r & 3) + 8 * (r >> 2) + 4 * half;
        float v = a[r] + bv;
        if (RELU) v = fmaxf(v, 0.0f);
        outb[(size_t)m * N + n] = __float2bfloat16(v);
        if (DUAL_OUT) {
          if (m < MREAL) outf[(size_t)m * N + n] = v;
        }
      }
    }
  }
}

// ---------------- router GEMM: logits = (Xhat @ Ww^T + Wb) * pi ----------------
// A: (MPAD, 1024) bf16, B: (64, 1024) bf16. 64x64 tile, 256 threads, 16x16x32.
__global__ __launch_bounds__(256)
void gemm_router(const bf16* __restrict__ A, const bf16* __restrict__ B,
                 const float* __restrict__ Wb, const float* __restrict__ pi,
                 float* __restrict__ out) {
  const int K = DD;
  __shared__ alignas(16) bf16 As[64 * 32];
  __shared__ alignas(16) bf16 Bs[64 * 32];
  const int tid  = threadIdx.x;
  const int wave = tid >> 6;
  const int lane = tid & 63;
  const int bm = blockIdx.x * 64;
  const int srow = wave * 16 + (lane >> 2);
  const int scol = (lane & 3) * 8;
  const bf16* gA = A + (size_t)(bm + srow) * K + scol;
  const bf16* gB = B + (size_t)srow * K + scol;
  bf16* lA = &As[srow * 32 + scol];
  bf16* lB = &Bs[srow * 32 + scol];
  const int lr = lane & 15;
  const int quad = lane >> 4;
  f32x4 acc[4] = {};
  for (int k0 = 0; k0 < K; k0 += 32) {
    __syncthreads();
    gload_lds16(gA + k0, lA);
    gload_lds16(gB + k0, lB);
    __syncthreads();
    bf16x8 af = *reinterpret_cast<const bf16x8*>(&As[(wave * 16 + lr) * 32 + quad * 8]);
#pragma unroll
    for (int j = 0; j < 4; ++j) {
      bf16x8 bf_ = *reinterpret_cast<const bf16x8*>(&Bs[(j * 16 + lr) * 32 + quad * 8]);
      acc[j] = __builtin_amdgcn_mfma_f32_16x16x32_bf16(af, bf_, acc[j], 0, 0, 0);
    }
  }
#pragma unroll
  for (int j = 0; j < 4; ++j) {
    const int e = j * 16 + lr;
    const float wb = Wb[e], pv = pi[e];
#pragma unroll
    for (int r = 0; r < 4; ++r) {
      const int m = bm + wave * 16 + quad * 4 + r;
      if (m < MREAL) out[(size_t)m * EE + e] = (acc[j][r] + wb) * pv;
    }
  }
}

extern "C" void kernel_launch(void* const* d_in, const int* in_sizes, int n_in,
                              void* d_out, int out_size, void* d_ws, size_t ws_size,
                              hipStream_t stream) {
  const float* seq      = (const float*)d_in[0];
  const float* pi       = (const float*)d_in[1];
  const float* beta_raw = (const float*)d_in[2];
  const float* p1_w     = (const float*)d_in[3];
  const float* p1_b     = (const float*)d_in[4];
  const float* p2_w     = (const float*)d_in[5];
  const float* p2_b     = (const float*)d_in[6];
  const float* W_w      = (const float*)d_in[7];
  const float* W_b      = (const float*)d_in[8];

  // workspace layout (bytes); Xhat_bf16 aliases A (A dead after GEMM1)
  constexpr size_t A_off    = 0;
  constexpr size_t A_sz     = (size_t)MPAD * 2 * DD * sizeof(bf16);   //  64 MiB
  constexpr size_t W1_off   = A_off + A_sz;
  constexpr size_t W1_sz    = (size_t)4 * DD * 2 * DD * sizeof(bf16); //  16 MiB
  constexpr size_t HID_off  = W1_off + W1_sz;
  constexpr size_t HID_sz   = (size_t)MPAD * 4 * DD * sizeof(bf16);   // 128 MiB
  constexpr size_t W2_off   = HID_off + HID_sz;
  constexpr size_t W2_sz    = (size_t)DD * 4 * DD * sizeof(bf16);     //   8 MiB
  constexpr size_t W3_off   = W2_off + W2_sz;
  constexpr size_t W3_sz    = (size_t)EE * DD * sizeof(bf16);
  constexpr size_t ENDS_off = W3_off + W3_sz;
  constexpr size_t ENDS_sz  = (size_t)NCHUNK * BB * DD * sizeof(float);
  constexpr size_t CARRY_off = ENDS_off + ENDS_sz;

  char* ws = (char*)d_ws;
  bf16*  Abuf = (bf16*)(ws + A_off);
  bf16*  W1   = (bf16*)(ws + W1_off);
  bf16*  HID  = (bf16*)(ws + HID_off);
  bf16*  W2   = (bf16*)(ws + W2_off);
  bf16*  W3   = (bf16*)(ws + W3_off);
  float* ENDS = (float*)(ws + ENDS_off);
  float* CARRY = (float*)(ws + CARRY_off);
  bf16*  XH   = (bf16*)(ws + A_off);  // alias of A

  float* out_logits = (float*)d_out;
  float* out_xhat   = out_logits + (size_t)MREAL * EE;

  // 1) weights -> bf16
  f2b<<<(4 * DD * 2 * DD / 8 + 255) / 256, 256, 0, stream>>>(p1_w, W1, 4 * DD * 2 * DD);
  f2b<<<(DD * 4 * DD / 8 + 255) / 256, 256, 0, stream>>>(p2_w, W2, DD * 4 * DD);
  f2b<<<(EE * DD / 8 + 255) / 256, 256, 0, stream>>>(W_w, W3, EE * DD);

  // 2) EMA scan (chunked 3-pass) -> A = [x | h] bf16
  ema_ends<<<NCHUNK * BB * DD / 256, 256, 0, stream>>>(seq, beta_raw, ENDS);
  ema_carry<<<BB * DD / 256, 256, 0, stream>>>(ENDS, beta_raw, CARRY);
  ema_write<<<NCHUNK * BB * DD / 256, 256, 0, stream>>>(seq, beta_raw, CARRY, Abuf);
  (void)hipMemsetAsync(ws + A_off + (size_t)MREAL * 2 * DD * sizeof(bf16), 0,
                       (size_t)(MPAD - MREAL) * 2 * DD * sizeof(bf16), stream);

  // 3) GEMM1: hid = relu(A @ p1_w^T + b1)   (16384 x 4096, K=2048)
  gemm_bt<true, false><<<dim3(4 * DD / 128, MPAD / 128), 256, 0, stream>>>(
      Abuf, W1, p1_b, HID, nullptr, 4 * DD, 2 * DD);

  // 4) GEMM2: x_hat = hid @ p2_w^T + b2     (16384 x 1024, K=4096) -> f32 out + bf16 ws
  gemm_bt<false, true><<<dim3(DD / 128, MPAD / 128), 256, 0, stream>>>(
      HID, W2, p2_b, XH, out_xhat, DD, 4 * DD);

  // 5) GEMM3: logits = (x_hat @ W_w^T + W_b) * pi   (16368 x 64, K=1024)
  gemm_router<<<MPAD / 64, 256, 0, stream>>>(XH, W3, W_b, pi, out_logits);
}

// Round 4
// 655.581 us; speedup vs baseline: 1.2589x; 1.1031x over previous
//
#include <hip/hip_runtime.h>
#include <hip/hip_bf16.h>
#include <cstdint>
#include <cstddef>

using bf16 = __hip_bfloat16;
typedef __bf16 bf16x8 __attribute__((ext_vector_type(8)));
typedef float f32x4 __attribute__((ext_vector_type(4)));
typedef float f32x16 __attribute__((ext_vector_type(16)));

// ---- constants for this problem ----
#define BB 16
#define TT 1024
#define DD 1024
#define EE 64
#define MREAL 16368   // (TT-1)*BB
#define MPAD  16384
#define NCHUNK 16
#define CHUNK 64

__device__ __forceinline__ void gload_lds16(const void* g, void* l) {
  __builtin_amdgcn_global_load_lds((const __attribute__((address_space(1))) void*)g,
                                   (__attribute__((address_space(3))) void*)l,
                                   16, 0, 0);
}

__device__ __forceinline__ float sigmoidf_(float x) {
  return 1.0f / (1.0f + __expf(-x));
}

// ---------------- fp32 -> bf16 weight conversion (8 elems/thread, 16B store) ----
__global__ void f2b(const float* __restrict__ src, bf16* __restrict__ dst, int n) {
  int i = (blockIdx.x * blockDim.x + threadIdx.x) * 8;
  if (i < n) {
    float4 v0 = *reinterpret_cast<const float4*>(src + i);
    float4 v1 = *reinterpret_cast<const float4*>(src + i + 4);
    alignas(16) bf16 tmp[8];
    tmp[0] = __float2bfloat16(v0.x); tmp[1] = __float2bfloat16(v0.y);
    tmp[2] = __float2bfloat16(v0.z); tmp[3] = __float2bfloat16(v0.w);
    tmp[4] = __float2bfloat16(v1.x); tmp[5] = __float2bfloat16(v1.y);
    tmp[6] = __float2bfloat16(v1.z); tmp[7] = __float2bfloat16(v1.w);
    *reinterpret_cast<float4*>(dst + i) = *reinterpret_cast<const float4*>(tmp);
  }
}

// ---------------- EMA pass 1: chunk-local endpoints ----------------
__global__ void ema_ends(const float* __restrict__ seq, const float* __restrict__ beta_raw,
                         float* __restrict__ ends) {
  int tid = blockIdx.x * blockDim.x + threadIdx.x;
  int d = tid & (DD - 1);
  int b = (tid >> 10) & (BB - 1);
  int c = tid >> 14;
  float beta = sigmoidf_(beta_raw[d]);
  int t0 = c * CHUNK;
  int len = min(CHUNK, (TT - 1) - t0);
  const float* p = seq + (size_t)b * TT * DD + (size_t)t0 * DD + d;
  float h = 0.0f;
#pragma unroll 8
  for (int j = 0; j < len; ++j) h = fmaf(beta, h, p[(size_t)j * DD]);
  ends[tid] = h;
}

// ---------------- EMA pass 2: carry combine (per chain) ----------------
__global__ void ema_carry(const float* __restrict__ ends, const float* __restrict__ beta_raw,
                          float* __restrict__ carry) {
  int tid = blockIdx.x * blockDim.x + threadIdx.x;
  int d = tid & (DD - 1);
  float beta = sigmoidf_(beta_raw[d]);
  float bl = beta;
  bl *= bl; bl *= bl; bl *= bl; bl *= bl; bl *= bl; bl *= bl;  // beta^64
  float run = 0.0f;
#pragma unroll
  for (int c = 0; c < NCHUNK; ++c) {
    carry[c * (BB * DD) + tid] = run;
    run = ends[c * (BB * DD) + tid] + bl * run;
  }
}

// ---------------- EMA pass 3: recompute + write A = [x | h] in bf16 ----------------
__global__ void ema_write(const float* __restrict__ seq, const float* __restrict__ beta_raw,
                          const float* __restrict__ carry, bf16* __restrict__ A) {
  int tid = blockIdx.x * blockDim.x + threadIdx.x;
  int d = tid & (DD - 1);
  int b = (tid >> 10) & (BB - 1);
  int c = tid >> 14;
  float beta = sigmoidf_(beta_raw[d]);
  int t0 = c * CHUNK;
  int len = min(CHUNK, (TT - 1) - t0);
  const float* p = seq + (size_t)b * TT * DD + (size_t)t0 * DD + d;
  float h = carry[tid];
#pragma unroll 4
  for (int j = 0; j < len; ++j) {
    float x = p[(size_t)j * DD];
    h = fmaf(beta, h, x);
    size_t m = (size_t)(t0 + j) * BB + b;
    A[m * (2 * DD) + d]      = __float2bfloat16(x);
    A[m * (2 * DD) + DD + d] = __float2bfloat16(h);
  }
}

// ---------------- main GEMM: C = act(A @ B^T + bias) ----------------
// A: (MPAD, K) bf16 row-major. B: (N, K) bf16 row-major.
// Macro-tile 128(M)x256(N), BK=64, 256 threads = 4 waves in 2(M)x2(N).
// Wave-tile 64x128 = 2x4 frags of 32x32x16 MFMA -> 6 LDS reads per 8 MFMAs.
// LDS XOR swizzle: physical colgroup(16B) = logical_cg ^ (row&7), rows 128B.
// grid.x = N/256 (fast; weights L2-resident), grid.y = MPAD/128.
template <bool RELU, bool DUAL_OUT>
__global__ __launch_bounds__(256, 2)
void gemm_bt(const bf16* __restrict__ A, const bf16* __restrict__ B,
             const float* __restrict__ bias, bf16* __restrict__ outb,
             float* __restrict__ outf, int N, int K) {
  __shared__ alignas(16) bf16 As[128 * 64];
  __shared__ alignas(16) bf16 Bs[256 * 64];
  const int tid  = threadIdx.x;
  const int wave = tid >> 6;
  const int lane = tid & 63;
  const int bm = blockIdx.y * 128;
  const int bn = blockIdx.x * 256;

  // --- staging: wave w fills As rows [w*32,w*32+32) (4 instrs) and
  // Bs rows [w*64,w*64+64) (8 instrs); each instr = 8 rows x 128 B.
  // lane l -> row +(l>>3), physical cg = l&7, source logical cg = (l&7)^(l>>3).
  const int srow8 = lane >> 3;                 // 0..7
  const int scg   = (lane & 7) ^ srow8;        // swizzled source colgroup
  const bf16* gA = A + (size_t)(bm + wave * 32 + srow8) * K + scg * 8;
  const bf16* gB = B + (size_t)(bn + wave * 64 + srow8) * K + scg * 8;
  bf16* lA = &As[(wave * 32 + srow8) * 64 + (lane & 7) * 8];
  bf16* lB = &Bs[(wave * 64 + srow8) * 64 + (lane & 7) * 8];

  // --- fragment addressing (32x32x16): m/n = lane&31, k = (lane>>5)*8+j
  const int lr   = lane & 31;
  const int half = lane >> 5;
  const int wm = (wave >> 1) * 64;
  const int wn = (wave & 1) * 128;
  int aoff[2], boff[4];
#pragma unroll
  for (int i = 0; i < 2; ++i) aoff[i] = (wm + i * 32 + lr) * 64;
#pragma unroll
  for (int j = 0; j < 4; ++j) boff[j] = (wn + j * 32 + lr) * 64;
  int swz[4];
#pragma unroll
  for (int kk = 0; kk < 4; ++kk) swz[kk] = ((kk * 2 + half) ^ (lr & 7)) * 8;

  f32x16 acc[2][4] = {};

  for (int k0 = 0; k0 < K; k0 += 64) {
    __syncthreads();
#pragma unroll
    for (int t = 0; t < 4; ++t)
      gload_lds16(gA + (size_t)t * 8 * K + k0, lA + t * 8 * 64);
#pragma unroll
    for (int t = 0; t < 8; ++t)
      gload_lds16(gB + (size_t)t * 8 * K + k0, lB + t * 8 * 64);
    __syncthreads();
#pragma unroll
    for (int kk = 0; kk < 4; ++kk) {
      bf16x8 a0 = *reinterpret_cast<const bf16x8*>(&As[aoff[0] + swz[kk]]);
      bf16x8 a1 = *reinterpret_cast<const bf16x8*>(&As[aoff[1] + swz[kk]]);
      bf16x8 b0 = *reinterpret_cast<const bf16x8*>(&Bs[boff[0] + swz[kk]]);
      bf16x8 b1 = *reinterpret_cast<const bf16x8*>(&Bs[boff[1] + swz[kk]]);
      bf16x8 b2 = *reinterpret_cast<const bf16x8*>(&Bs[boff[2] + swz[kk]]);
      bf16x8 b3 = *reinterpret_cast<const bf16x8*>(&Bs[boff[3] + swz[kk]]);
      acc[0][0] = __builtin_amdgcn_mfma_f32_32x32x16_bf16(a0, b0, acc[0][0], 0, 0, 0);
      acc[0][1] = __builtin_amdgcn_mfma_f32_32x32x16_bf16(a0, b1, acc[0][1], 0, 0, 0);
      acc[0][2] = __builtin_amdgcn_mfma_f32_32x32x16_bf16(a0, b2, acc[0][2], 0, 0, 0);
      acc[0][3] = __builtin_amdgcn_mfma_f32_32x32x16_bf16(a0, b3, acc[0][3], 0, 0, 0);
      acc[1][0] = __builtin_amdgcn_mfma_f32_32x32x16_bf16(a1, b0, acc[1][0], 0, 0, 0);
      acc[1][1] = __builtin_amdgcn_mfma_f32_32x32x16_bf16(a1, b1, acc[1][1], 0, 0, 0);
      acc[1][2] = __builtin_amdgcn_mfma_f32_32x32x16_bf16(a1, b2, acc[1][2], 0, 0, 0);
      acc[1][3] = __builtin_amdgcn_mfma_f32_32x32x16_bf16(a1, b3, acc[1][3], 0, 0, 0);
    }
  }

  // epilogue: C/D layout col = lane&31, row = (r&3) + 8*(r>>2) + 4*half
#pragma unroll
  for (int i = 0; i < 2; ++i) {
#pragma unroll
    for (int j = 0; j < 4; ++j) {
      const int n = bn + wn + j * 32 + lr;
      const float bv = bias[n];
#pragma unroll
      for (int r = 0; r < 16; ++r) {
        const int m = bm + wm + i * 32 + (r & 3) + 8 * (r >> 2) + 4 * half;
        float v = acc[i][j][r] + bv;
        if (RELU) v = fmaxf(v, 0.0f);
        outb[(size_t)m * N + n] = __float2bfloat16(v);
        if (DUAL_OUT) {
          if (m < MREAL) outf[(size_t)m * N + n] = v;
        }
      }
    }
  }
}

// ---------------- router GEMM: logits = (Xhat @ Ww^T + Wb) * pi ----------------
// A: (MPAD, 1024) bf16, B: (64, 1024) bf16. 64x64 tile, 256 threads, 16x16x32.
__global__ __launch_bounds__(256)
void gemm_router(const bf16* __restrict__ A, const bf16* __restrict__ B,
                 const float* __restrict__ Wb, const float* __restrict__ pi,
                 float* __restrict__ out) {
  const int K = DD;
  __shared__ alignas(16) bf16 As[64 * 32];
  __shared__ alignas(16) bf16 Bs[64 * 32];
  const int tid  = threadIdx.x;
  const int wave = tid >> 6;
  const int lane = tid & 63;
  const int bm = blockIdx.x * 64;
  const int srow = wave * 16 + (lane >> 2);
  const int scol = (lane & 3) * 8;
  const bf16* gA = A + (size_t)(bm + srow) * K + scol;
  const bf16* gB = B + (size_t)srow * K + scol;
  bf16* lA = &As[srow * 32 + scol];
  bf16* lB = &Bs[srow * 32 + scol];
  const int lr = lane & 15;
  const int quad = lane >> 4;
  f32x4 acc[4] = {};
  for (int k0 = 0; k0 < K; k0 += 32) {
    __syncthreads();
    gload_lds16(gA + k0, lA);
    gload_lds16(gB + k0, lB);
    __syncthreads();
    bf16x8 af = *reinterpret_cast<const bf16x8*>(&As[(wave * 16 + lr) * 32 + quad * 8]);
#pragma unroll
    for (int j = 0; j < 4; ++j) {
      bf16x8 bf_ = *reinterpret_cast<const bf16x8*>(&Bs[(j * 16 + lr) * 32 + quad * 8]);
      acc[j] = __builtin_amdgcn_mfma_f32_16x16x32_bf16(af, bf_, acc[j], 0, 0, 0);
    }
  }
#pragma unroll
  for (int j = 0; j < 4; ++j) {
    const int e = j * 16 + lr;
    const float wb = Wb[e], pv = pi[e];
#pragma unroll
    for (int r = 0; r < 4; ++r) {
      const int m = bm + wave * 16 + quad * 4 + r;
      if (m < MREAL) out[(size_t)m * EE + e] = (acc[j][r] + wb) * pv;
    }
  }
}

extern "C" void kernel_launch(void* const* d_in, const int* in_sizes, int n_in,
                              void* d_out, int out_size, void* d_ws, size_t ws_size,
                              hipStream_t stream) {
  const float* seq      = (const float*)d_in[0];
  const float* pi       = (const float*)d_in[1];
  const float* beta_raw = (const float*)d_in[2];
  const float* p1_w     = (const float*)d_in[3];
  const float* p1_b     = (const float*)d_in[4];
  const float* p2_w     = (const float*)d_in[5];
  const float* p2_b     = (const float*)d_in[6];
  const float* W_w      = (const float*)d_in[7];
  const float* W_b      = (const float*)d_in[8];

  // workspace layout (bytes); Xhat_bf16 aliases A (A dead after GEMM1)
  constexpr size_t A_off    = 0;
  constexpr size_t A_sz     = (size_t)MPAD * 2 * DD * sizeof(bf16);   //  64 MiB
  constexpr size_t W1_off   = A_off + A_sz;
  constexpr size_t W1_sz    = (size_t)4 * DD * 2 * DD * sizeof(bf16); //  16 MiB
  constexpr size_t HID_off  = W1_off + W1_sz;
  constexpr size_t HID_sz   = (size_t)MPAD * 4 * DD * sizeof(bf16);   // 128 MiB
  constexpr size_t W2_off   = HID_off + HID_sz;
  constexpr size_t W2_sz    = (size_t)DD * 4 * DD * sizeof(bf16);     //   8 MiB
  constexpr size_t W3_off   = W2_off + W2_sz;
  constexpr size_t W3_sz    = (size_t)EE * DD * sizeof(bf16);
  constexpr size_t ENDS_off = W3_off + W3_sz;
  constexpr size_t ENDS_sz  = (size_t)NCHUNK * BB * DD * sizeof(float);
  constexpr size_t CARRY_off = ENDS_off + ENDS_sz;

  char* ws = (char*)d_ws;
  bf16*  Abuf = (bf16*)(ws + A_off);
  bf16*  W1   = (bf16*)(ws + W1_off);
  bf16*  HID  = (bf16*)(ws + HID_off);
  bf16*  W2   = (bf16*)(ws + W2_off);
  bf16*  W3   = (bf16*)(ws + W3_off);
  float* ENDS = (float*)(ws + ENDS_off);
  float* CARRY = (float*)(ws + CARRY_off);
  bf16*  XH   = (bf16*)(ws + A_off);  // alias of A

  float* out_logits = (float*)d_out;
  float* out_xhat   = out_logits + (size_t)MREAL * EE;

  // 1) weights -> bf16
  f2b<<<(4 * DD * 2 * DD / 8 + 255) / 256, 256, 0, stream>>>(p1_w, W1, 4 * DD * 2 * DD);
  f2b<<<(DD * 4 * DD / 8 + 255) / 256, 256, 0, stream>>>(p2_w, W2, DD * 4 * DD);
  f2b<<<(EE * DD / 8 + 255) / 256, 256, 0, stream>>>(W_w, W3, EE * DD);

  // 2) EMA scan (chunked 3-pass) -> A = [x | h] bf16
  ema_ends<<<NCHUNK * BB * DD / 256, 256, 0, stream>>>(seq, beta_raw, ENDS);
  ema_carry<<<BB * DD / 256, 256, 0, stream>>>(ENDS, beta_raw, CARRY);
  ema_write<<<NCHUNK * BB * DD / 256, 256, 0, stream>>>(seq, beta_raw, CARRY, Abuf);
  (void)hipMemsetAsync(ws + A_off + (size_t)MREAL * 2 * DD * sizeof(bf16), 0,
                       (size_t)(MPAD - MREAL) * 2 * DD * sizeof(bf16), stream);

  // 3) GEMM1: hid = relu(A @ p1_w^T + b1)   (16384 x 4096, K=2048)
  gemm_bt<true, false><<<dim3(4 * DD / 256, MPAD / 128), 256, 0, stream>>>(
      Abuf, W1, p1_b, HID, nullptr, 4 * DD, 2 * DD);

  // 4) GEMM2: x_hat = hid @ p2_w^T + b2     (16384 x 1024, K=4096) -> f32 out + bf16 ws
  gemm_bt<false, true><<<dim3(DD / 256, MPAD / 128), 256, 0, stream>>>(
      HID, W2, p2_b, XH, out_xhat, DD, 4 * DD);

  // 5) GEMM3: logits = (x_hat @ W_w^T + W_b) * pi   (16368 x 64, K=1024)
  gemm_router<<<MPAD / 64, 256, 0, stream>>>(XH, W3, W_b, pi, out_logits);
}